// Round 4
// baseline (68.975 us; speedup 1.0000x reference)
//
#include <hip/hip_runtime.h>

// Chamfer distance, deterministic, no atomics, no memsets.
// pts = img_render_points[0]      : 4096 x 2 f32 (slice 0)
// refs = ref_catheter_skeleton[1] : 32768 x 2 f32 (last slice; flip is neutral)
//
// ||p-r||^2 = ||p||^2 + (||r||^2 - 2 p.r)
// LDS staged record: (-2*r.x, -2*r.y, ||r||^2, 0) -> one ds_read_b128 each.
// Register-block 16 own points/thread: 16 pairs per ds_read (8x fewer LDS ops
// than round 2), inner math 2 FMA/pair + amortized v_min3.

constexpr int N_PTS = 4096;
constexpr int M_REF = 32768;
constexpr int P_OWN = 16;   // own points per thread
constexpr int S_STG = 128;  // staged points per block (slice)

// Grid: 512 blocks x 256 threads.
//  rows (b < 256):  own = all 4096 pts (256 thr x 16), staged = refs slice b (128)
//  cols (b >= 256): own = refs chunk (bb&7)*4096 (256 thr x 16),
//                   staged = pts slice (bb>>3) (128)          [32 slices x 8 chunks]
__global__ __launch_bounds__(256) void chamfer_main_kernel(
    const float2* __restrict__ pts, const float2* __restrict__ refs,
    float* __restrict__ rowpart,   // [256][N_PTS]
    float* __restrict__ colpart)   // [32][M_REF]
{
    __shared__ float4 sh[S_STG];   // 2 KB
    const int tid = threadIdx.x, b = blockIdx.x;

    const float2* own; const float2* oth; float* part;
    int ownBase, sbase;
    if (b < 256) {                        // rows: own = pts, staged = refs
        own = pts;  oth = refs;
        ownBase = tid * P_OWN;            // covers all 4096 pts
        sbase   = b * S_STG;
        part    = rowpart + b * N_PTS + ownBase;
    } else {                              // cols: own = refs, staged = pts
        const int bb = b - 256;
        own = refs; oth = pts;
        ownBase = (bb & 7) * 4096 + tid * P_OWN;
        sbase   = (bb >> 3) * S_STG;
        part    = colpart + (bb >> 3) * M_REF + ownBase;
    }

    // Stage S_STG records (threads 0..127), computing (-2x,-2y,n2) on the fly.
    if (tid < S_STG) {
        const float2 r = oth[sbase + tid];
        sh[tid] = make_float4(-2.f * r.x, -2.f * r.y, fmaf(r.x, r.x, r.y * r.y), 0.f);
    }

    // Load 16 own points (8 x float4 = 128 B contiguous per thread).
    float px[P_OWN], py[P_OWN], mn[P_OWN];
    {
        const float4* o4 = (const float4*)(own + ownBase);
        #pragma unroll
        for (int q = 0; q < P_OWN / 2; ++q) {
            const float4 o = o4[q];
            px[2 * q]     = o.x; py[2 * q]     = o.y;
            px[2 * q + 1] = o.z; py[2 * q + 1] = o.w;
        }
        #pragma unroll
        for (int k = 0; k < P_OWN; ++k) mn[k] = 3.0e38f;
    }
    __syncthreads();

    for (int j = 0; j < S_STG; j += 4) {   // broadcast ds_read_b128 x4 per iter
        const float4 r0 = sh[j];
        const float4 r1 = sh[j + 1];
        const float4 r2 = sh[j + 2];
        const float4 r3 = sh[j + 3];
        #pragma unroll
        for (int k = 0; k < P_OWN; ++k) {
            const float d0 = fmaf(px[k], r0.x, fmaf(py[k], r0.y, r0.z));
            const float d1 = fmaf(px[k], r1.x, fmaf(py[k], r1.y, r1.z));
            const float d2 = fmaf(px[k], r2.x, fmaf(py[k], r2.y, r2.z));
            const float d3 = fmaf(px[k], r3.x, fmaf(py[k], r3.y, r3.z));
            mn[k] = fminf(fminf(mn[k], d0), d1);   // v_min3_f32
            mn[k] = fminf(fminf(mn[k], d2), d3);   // v_min3_f32
        }
    }

    // 64 B contiguous per thread, written exactly once: no init needed.
    float4* w = (float4*)part;
    #pragma unroll
    for (int q = 0; q < P_OWN / 4; ++q)
        w[q] = make_float4(mn[4 * q], mn[4 * q + 1], mn[4 * q + 2], mn[4 * q + 3]);
}

// ---------------- Kernel 2: fold slices, add ||own||^2, sqrt, block sums ---
// 144 blocks x 256: blocks 0..15 -> pts (4096, 256 slices),
//                   blocks 16..143 -> refs (32768, 32 slices)
__global__ __launch_bounds__(256) void chamfer_fold_kernel(
    const float2* __restrict__ pts, const float2* __restrict__ refs,
    const float* __restrict__ rowpart, const float* __restrict__ colpart,
    float* __restrict__ blocksum)   // [144]
{
    __shared__ float ssum[4];
    const int tid = threadIdx.x, b = blockIdx.x;
    float d;
    if (b < 16) {
        const int pt = b * 256 + tid;
        float m = 3.0e38f;
        #pragma unroll 8
        for (int s = 0; s < 256; ++s) m = fminf(m, rowpart[s * N_PTS + pt]);
        const float2 p = pts[pt];
        d = sqrtf(fmaxf(m + fmaf(p.x, p.x, p.y * p.y), 1e-12f));
    } else {
        const int idx = (b - 16) * 256 + tid;
        float m = 3.0e38f;
        #pragma unroll
        for (int s = 0; s < 32; ++s) m = fminf(m, colpart[s * M_REF + idx]);
        const float2 r = refs[idx];
        d = sqrtf(fmaxf(m + fmaf(r.x, r.x, r.y * r.y), 1e-12f));
    }
    #pragma unroll
    for (int off = 32; off > 0; off >>= 1) d += __shfl_down(d, off, 64);
    const int lane = tid & 63, wave = tid >> 6;
    if (lane == 0) ssum[wave] = d;
    __syncthreads();
    if (tid == 0) blocksum[b] = ssum[0] + ssum[1] + ssum[2] + ssum[3];
}

// ---------------- Kernel 3: final sum (plain store) ------------------------
__global__ __launch_bounds__(256) void chamfer_final_kernel(
    const float* __restrict__ blocksum, float* __restrict__ out)
{
    __shared__ float ssum[4];
    const int tid = threadIdx.x;
    float d = (tid < 144) ? blocksum[tid] : 0.f;
    #pragma unroll
    for (int off = 32; off > 0; off >>= 1) d += __shfl_down(d, off, 64);
    const int lane = tid & 63, wave = tid >> 6;
    if (lane == 0) ssum[wave] = d;
    __syncthreads();
    if (tid == 0) out[0] = ssum[0] + ssum[1] + ssum[2] + ssum[3];
}

extern "C" void kernel_launch(void* const* d_in, const int* in_sizes, int n_in,
                              void* d_out, int out_size, void* d_ws, size_t ws_size,
                              hipStream_t stream) {
    const float2* pts  = (const float2*)d_in[0];            // circle 0 (offset 0)
    const float2* refs = ((const float2*)d_in[1]) + M_REF;  // last (=2nd) skeleton slice

    float* rowpart  = (float*)d_ws;                         // 256*4096 f32 = 4 MB
    float* colpart  = rowpart + 256 * N_PTS;                //  32*32768 f32 = 4 MB
    float* blocksum = colpart + 32 * M_REF;                 // 144 f32
    float* out = (float*)d_out;

    chamfer_main_kernel <<<512, 256, 0, stream>>>(pts, refs, rowpart, colpart);
    chamfer_fold_kernel <<<144, 256, 0, stream>>>(pts, refs, rowpart, colpart, blocksum);
    chamfer_final_kernel<<<1, 256, 0, stream>>>(blocksum, out);
}